// Round 5
// baseline (31766.840 us; speedup 1.0000x reference)
//
#include <hip/hip_runtime.h>
#include <math.h>

#define BB 32
#define TT 1000
#define HH 512
#define JJ 512
#define VV 1024
#define G4 2048
#define NB 128
#define NT 1024

#define RLX __ATOMIC_RELAXED
#define AGT __HIP_MEMORY_SCOPE_AGENT

// ---- persistent device-side scratch ----
__device__ __align__(16) float g_encp[(size_t)TT * JJ * BB];  // [t][j][b]
__device__ __align__(16) float g_E[(size_t)VV * G4];          // [v][g]
__device__ __align__(16) float g_h[HH * BB];                  // [k][b] (== out_PN)
__device__ __align__(16) float g_c[BB * HH];                  // [b][k]
__device__ __align__(16) float g_joint[JJ * BB];              // [j][b]
__device__ __align__(16) float g_hW[BB * G4];                 // [b][g]
__device__ float g_pm[BB * NB];                               // [b][blk] partial max
__device__ float g_ps[BB * NB];                               // [b][blk] partial sumexp
__device__ int   g_pa[BB * NB];                               // [b][blk] partial argmax
__device__ float g_score[BB];
// RMW-free barrier: per-block arrival slots, monotonic step tags, per phase
__device__ int g_arr[3][NB];

// ---------------- K0: enc_proj[t][j][b] ----------------
__global__ __launch_bounds__(256) void k_encproj(const float* __restrict__ enc,
                                                 const float* __restrict__ Wenc) {
    __shared__ __align__(16) float x[BB * 512];
    const int t = blockIdx.x;
    for (int i = threadIdx.x; i < BB * 128; i += 256) {
        const int b = i >> 7, k4 = i & 127;
        *reinterpret_cast<float4*>(x + b * 512 + k4 * 4) =
            *reinterpret_cast<const float4*>(enc + ((size_t)(b * TT + t)) * 512 + k4 * 4);
    }
    __syncthreads();
    const int j = threadIdx.x;
    float acc0[BB], acc1[BB];
#pragma unroll
    for (int b = 0; b < BB; ++b) { acc0[b] = 0.f; acc1[b] = 0.f; }
    for (int k4 = 0; k4 < 128; ++k4) {
        const int k = k4 * 4;
        float w0[4], w1[4];
#pragma unroll
        for (int i = 0; i < 4; ++i) {
            w0[i] = Wenc[(size_t)(k + i) * JJ + j];
            w1[i] = Wenc[(size_t)(k + i) * JJ + j + 256];
        }
#pragma unroll
        for (int b = 0; b < BB; ++b) {
            const float4 xv = *reinterpret_cast<const float4*>(x + b * 512 + k);
            acc0[b] += xv.x * w0[0] + xv.y * w0[1] + xv.z * w0[2] + xv.w * w0[3];
            acc1[b] += xv.x * w1[0] + xv.y * w1[1] + xv.z * w1[2] + xv.w * w1[3];
        }
    }
    float* outt = g_encp + (size_t)t * JJ * BB;
#pragma unroll
    for (int b = 0; b < BB; ++b) {
        outt[j * BB + b]         = acc0[b];
        outt[(j + 256) * BB + b] = acc1[b];
    }
}

// ---------------- K1: E = embed @ W_ih ----------------
__global__ __launch_bounds__(256) void k_embproj(const float* __restrict__ emb,
                                                 const float* __restrict__ Wih) {
    __shared__ __align__(16) float x[BB * 512];
    const int v0 = (blockIdx.x >> 2) * 32;
    const int g0 = (blockIdx.x & 3) * 512;
    for (int i = threadIdx.x; i < BB * 128; i += 256) {
        const int b = i >> 7, k4 = i & 127;
        *reinterpret_cast<float4*>(x + b * 512 + k4 * 4) =
            *reinterpret_cast<const float4*>(emb + (size_t)(v0 + b) * 512 + k4 * 4);
    }
    __syncthreads();
    const int j = g0 + threadIdx.x;
    float acc0[BB], acc1[BB];
#pragma unroll
    for (int b = 0; b < BB; ++b) { acc0[b] = 0.f; acc1[b] = 0.f; }
    for (int k4 = 0; k4 < 128; ++k4) {
        const int k = k4 * 4;
        float w0[4], w1[4];
#pragma unroll
        for (int i = 0; i < 4; ++i) {
            w0[i] = Wih[(size_t)(k + i) * G4 + j];
            w1[i] = Wih[(size_t)(k + i) * G4 + j + 256];
        }
#pragma unroll
        for (int b = 0; b < BB; ++b) {
            const float4 xv = *reinterpret_cast<const float4*>(x + b * 512 + k);
            acc0[b] += xv.x * w0[0] + xv.y * w0[1] + xv.z * w0[2] + xv.w * w0[3];
            acc1[b] += xv.x * w1[0] + xv.y * w1[1] + xv.z * w1[2] + xv.w * w1[3];
        }
    }
#pragma unroll
    for (int b = 0; b < BB; ++b) {
        g_E[(size_t)(v0 + b) * G4 + j]       = acc0[b];
        g_E[(size_t)(v0 + b) * G4 + j + 256] = acc1[b];
    }
}

// ---------------- K2: initial LSTM step + state/barrier reset ----------------
__global__ void k_init(const float* __restrict__ bl) {
    const int k = threadIdx.x;  // 512
    const float ig = g_E[k]        + bl[k];
    const float gg = g_E[1024 + k] + bl[1024 + k];
    const float og = g_E[1536 + k] + bl[1536 + k];
    const float si = 1.f / (1.f + expf(-ig));
    const float so = 1.f / (1.f + expf(-og));
    const float c1 = si * tanhf(gg);
    const float h1 = so * tanhf(c1);
    for (int b = 0; b < BB; ++b) {
        g_h[k * BB + b] = h1;
        g_c[b * HH + k] = c1;
    }
    if (k < BB) g_score[k] = 0.f;
    if (k < 3 * NB) ((int*)g_arr)[k] = 0;
}

// 4-col x 32-b tile, K covered by ks-interleaved slices (k = k0 + i*8 + ks).
// w rows padded to `wpad` floats -> conflict-free. Butterfly over ks bits
// leaves the (partial-)K sums in ALL lanes.
template<int KN>
__device__ __forceinline__ void mv4(const float* __restrict__ w_lds, const int wpad,
                                    const int c0, const int k0,
                                    const float* __restrict__ x_lds,
                                    const int ks, const int b4, float acc[4][4]) {
#pragma unroll
    for (int c = 0; c < 4; ++c)
#pragma unroll
        for (int r = 0; r < 4; ++r) acc[c][r] = 0.f;
#pragma unroll 8
    for (int i = 0; i < KN; ++i) {
        const int k = k0 + i * 8 + ks;
        const float4 xv = *reinterpret_cast<const float4*>(x_lds + k * 32 + b4 * 4);
        const float4 wv = *reinterpret_cast<const float4*>(w_lds + k * wpad + c0);
        acc[0][0] += wv.x * xv.x; acc[0][1] += wv.x * xv.y; acc[0][2] += wv.x * xv.z; acc[0][3] += wv.x * xv.w;
        acc[1][0] += wv.y * xv.x; acc[1][1] += wv.y * xv.y; acc[1][2] += wv.y * xv.z; acc[1][3] += wv.y * xv.w;
        acc[2][0] += wv.z * xv.x; acc[2][1] += wv.z * xv.y; acc[2][2] += wv.z * xv.z; acc[2][3] += wv.z * xv.w;
        acc[3][0] += wv.w * xv.x; acc[3][1] += wv.w * xv.y; acc[3][2] += wv.w * xv.z; acc[3][3] += wv.w * xv.w;
    }
#pragma unroll
    for (int off = 8; off <= 32; off <<= 1)
#pragma unroll
        for (int c = 0; c < 4; ++c)
#pragma unroll
            for (int r = 0; r < 4; ++r) acc[c][r] += __shfl_xor(acc[c][r], off, 64);
}

// ---------------- K3: persistent scan, RMW-free barriers ----------------
__global__ __launch_bounds__(NT) void k_loop(const float* __restrict__ Wdec,
                                             const float* __restrict__ Wout,
                                             const float* __restrict__ Whh,
                                             const float* __restrict__ bj,
                                             const float* __restrict__ bl,
                                             float* __restrict__ out) {
    __shared__ __align__(16) float x_lds[512 * 32];     // 64 KB: h, then joint
    __shared__ __align__(16) float wab_lds[512 * 20];   // 40 KB: cols 0-15 Whh, 16-19 Wdec
    __shared__ __align__(16) float wout_lds[512 * 12];  // 24 KB: cols 0-7 Wout
    __shared__ float part_lds[560];                     // A: 4x136 quarters; B: 2x160 halves
    __shared__ float logit_lds[8 * 33];
    __shared__ float red_m[2], red_s[2];
    __shared__ int   red_a[2];
    __shared__ int   red_bar[2];
    __shared__ int   bar_done;

    const int blk = blockIdx.x, tid = threadIdx.x;
    const int wv = tid >> 6, lane = tid & 63, ks = lane >> 3, b4 = lane & 7;
    const int row = blk >> 2, qs = blk & 3;   // window-C assignment

    for (int i = tid; i < 512 * 20; i += NT) {
        const int k = i / 20, c = i - k * 20;
        wab_lds[i] = (c < 16) ? Whh[(size_t)k * G4 + blk * 16 + c]
                              : Wdec[(size_t)k * JJ + blk * 4 + (c - 16)];
    }
    for (int i = tid; i < 512 * 12; i += NT) {
        const int k = i / 12, c = i - k * 12;
        wout_lds[i] = (c < 8) ? Wout[(size_t)k * VV + blk * 8 + c] : 0.f;
    }
    float bjr[4];
#pragma unroll
    for (int c = 0; c < 4; ++c) bjr[c] = bj[blk * 4 + c];
    __syncthreads();

    float acc[4][4];
    for (int t = 0; t < TT; ++t) {
        const int tp1 = t + 1;
        // ======== window A: stage h; Whh waves 0-3; Wdec quarter-K waves 4-7 -> joint
        {
            float v[16];
#pragma unroll
            for (int p = 0; p < 16; ++p)
                v[p] = __hip_atomic_load(&g_h[tid + p * 1024], RLX, AGT);
#pragma unroll
            for (int p = 0; p < 16; ++p) x_lds[tid + p * 1024] = v[p];
        }
        float encr[4];
        if (wv == 8 && lane < 32) {   // early enc prefetch (normal cached loads)
            const float* ep = g_encp + (size_t)t * JJ * BB + (size_t)blk * 4 * BB;
#pragma unroll
            for (int c = 0; c < 4; ++c) encr[c] = ep[c * BB + lane];
        }
        __syncthreads();
        if (wv < 4) {                 // hW slice: 4 cols each, full K
            mv4<64>(wab_lds, 20, wv * 4, 0, x_lds, ks, b4, acc);
            if (ks == 0) {
#pragma unroll
                for (int c = 0; c < 4; ++c)
#pragma unroll
                    for (int j = 0; j < 4; ++j)
                        __hip_atomic_store(&g_hW[(size_t)(b4 * 4 + j) * G4 + blk * 16 + wv * 4 + c],
                                           acc[c][j], RLX, AGT);
            }
        } else if (wv < 8) {          // Wdec quarter-K partials
            mv4<16>(wab_lds, 20, 16, (wv - 4) * 128, x_lds, ks, b4, acc);
            if (ks == 0) {
#pragma unroll
                for (int c = 0; c < 4; ++c)
#pragma unroll
                    for (int j = 0; j < 4; ++j)
                        part_lds[(wv - 4) * 136 + c * 33 + b4 * 4 + j] = acc[c][j];
            }
        }
        __syncthreads();
        if (wv == 8 && lane < 32) {   // combine quarters + enc + bias -> joint
            const int b = lane;
#pragma unroll
            for (int c = 0; c < 4; ++c) {
                const float u = part_lds[c * 33 + b] + part_lds[136 + c * 33 + b]
                              + part_lds[272 + c * 33 + b] + part_lds[408 + c * 33 + b]
                              + encr[c] + bjr[c];
                __hip_atomic_store(&g_joint[(blk * 4 + c) * BB + b], tanhf(u), RLX, AGT);
            }
        }
        // -------- barrier 0 (arrive: store own slot; wait: self-gather min) --------
        __syncthreads();              // drains all stores (vmcnt 0) before arrival tag
        if (tid == 0) __hip_atomic_store(&g_arr[0][blk], tp1, RLX, AGT);
        for (;;) {
            int m = 0x7fffffff;
            if (tid < NB) m = __hip_atomic_load(&g_arr[0][tid], RLX, AGT);
#pragma unroll
            for (int off = 32; off; off >>= 1) m = min(m, __shfl_xor(m, off, 64));
            if (lane == 0 && wv < 2) red_bar[wv] = m;
            __syncthreads();
            if (tid == 0) bar_done = (min(red_bar[0], red_bar[1]) >= tp1);
            __syncthreads();
            if (bar_done) break;
            __builtin_amdgcn_s_sleep(1);
        }

        // ======== window B: stage joint; Wout tiles waves 0-3 -> logits -> stats
        {
            float v[16];
#pragma unroll
            for (int p = 0; p < 16; ++p)
                v[p] = __hip_atomic_load(&g_joint[tid + p * 1024], RLX, AGT);
#pragma unroll
            for (int p = 0; p < 16; ++p) x_lds[tid + p * 1024] = v[p];
        }
        __syncthreads();
        if (wv < 4) {
            const int tile = wv & 1, kh = wv >> 1;
            mv4<32>(wout_lds, 12, tile * 4, kh * 256, x_lds, ks, b4, acc);
            if (kh == 1 && ks == 0) {
#pragma unroll
                for (int c = 0; c < 4; ++c)
#pragma unroll
                    for (int j = 0; j < 4; ++j)
                        part_lds[tile * 160 + c * 33 + b4 * 4 + j] = acc[c][j];
            }
        }
        __syncthreads();
        if (wv < 2 && ks == 0) {      // combine K-halves, stash logits
#pragma unroll
            for (int c = 0; c < 4; ++c)
#pragma unroll
                for (int j = 0; j < 4; ++j)
                    logit_lds[(wv * 4 + c) * 33 + b4 * 4 + j] =
                        acc[c][j] + part_lds[wv * 160 + c * 33 + b4 * 4 + j];
        }
        __syncthreads();
        if (wv == 0 && lane < BB) {   // per-b stats over this block's 8 cols
            const int b = lane;
            float m = -1e30f; int a = 0;
#pragma unroll
            for (int c = 0; c < 8; ++c) {
                const float l = logit_lds[c * 33 + b];
                if (l > m) { m = l; a = blk * 8 + c; }
            }
            float s = 0.f;
#pragma unroll
            for (int c = 0; c < 8; ++c) s += expf(logit_lds[c * 33 + b] - m);
            __hip_atomic_store(&g_pm[b * NB + blk], m, RLX, AGT);
            __hip_atomic_store(&g_pa[b * NB + blk], a, RLX, AGT);
            __hip_atomic_store(&g_ps[b * NB + blk], s, RLX, AGT);
        }
        // -------- barrier 1 --------
        __syncthreads();
        if (tid == 0) __hip_atomic_store(&g_arr[1][blk], tp1, RLX, AGT);
        for (;;) {
            int m = 0x7fffffff;
            if (tid < NB) m = __hip_atomic_load(&g_arr[1][tid], RLX, AGT);
#pragma unroll
            for (int off = 32; off; off >>= 1) m = min(m, __shfl_xor(m, off, 64));
            if (lane == 0 && wv < 2) red_bar[wv] = m;
            __syncthreads();
            if (tid == 0) bar_done = (min(red_bar[0], red_bar[1]) >= tp1);
            __syncthreads();
            if (bar_done) break;
            __builtin_amdgcn_s_sleep(1);
        }

        // ======== window C: all blocks. block 4r+q: reduce row r stats, LSTM k-slice q
        {
            float m0 = -1e30f, s0 = 0.f; int a0 = 1 << 30;
            if (tid < NB) {
                m0 = __hip_atomic_load(&g_pm[row * NB + tid], RLX, AGT);
                a0 = __hip_atomic_load(&g_pa[row * NB + tid], RLX, AGT);
                s0 = __hip_atomic_load(&g_ps[row * NB + tid], RLX, AGT);
            }
            float m = m0; int a = a0;
#pragma unroll
            for (int off = 32; off; off >>= 1) {
                const float om = __shfl_xor(m, off, 64);
                const int   oa = __shfl_xor(a, off, 64);
                if (om > m || (om == m && oa < a)) { m = om; a = oa; }
            }
            if (lane == 0 && wv < 2) { red_m[wv] = m; red_a[wv] = a; }
            __syncthreads();
            float M; int P;
            {
                const float ma = red_m[0], mb = red_m[1];
                const int aa = red_a[0], ab = red_a[1];
                if (mb > ma || (mb == ma && ab < aa)) { M = mb; P = ab; }
                else { M = ma; P = aa; }
            }
            float e = (tid < NB) ? s0 * expf(m0 - M) : 0.f;
#pragma unroll
            for (int off = 32; off; off >>= 1) e += __shfl_xor(e, off, 64);
            if (lane == 0 && wv < 2) red_s[wv] = e;
            __syncthreads();
            if (qs == 0 && tid == 0) {
                out[row * TT + t] = (float)P;
                if (P != 0) g_score[row] += -logf(red_s[0] + red_s[1]);
            }
            if (P != 0 && tid < 128) {   // LSTM k-slice: k in [qs*128, qs*128+128)
                const int k = qs * 128 + tid;
                const float* Ep = g_E + (size_t)P * G4;
                const float hw0 = __hip_atomic_load(&g_hW[(size_t)row * G4 + k],        RLX, AGT);
                const float hw1 = __hip_atomic_load(&g_hW[(size_t)row * G4 + 512 + k],  RLX, AGT);
                const float hw2 = __hip_atomic_load(&g_hW[(size_t)row * G4 + 1024 + k], RLX, AGT);
                const float hw3 = __hip_atomic_load(&g_hW[(size_t)row * G4 + 1536 + k], RLX, AGT);
                const float i_g = Ep[k]        + hw0 + bl[k];
                const float f_g = Ep[512 + k]  + hw1 + bl[512 + k];
                const float g_g = Ep[1024 + k] + hw2 + bl[1024 + k];
                const float o_g = Ep[1536 + k] + hw3 + bl[1536 + k];
                const float si = 1.f / (1.f + expf(-i_g));
                const float sf = 1.f / (1.f + expf(-f_g));
                const float so = 1.f / (1.f + expf(-o_g));
                const float cn = sf * g_c[row * HH + k] + si * tanhf(g_g);
                const float hn = so * tanhf(cn);
                g_c[row * HH + k] = cn;                          // block-private
                __hip_atomic_store(&g_h[k * BB + row], hn, RLX, AGT);
            }
        }
        // -------- barrier 2 --------
        __syncthreads();
        if (tid == 0) __hip_atomic_store(&g_arr[2][blk], tp1, RLX, AGT);
        for (;;) {
            int m = 0x7fffffff;
            if (tid < NB) m = __hip_atomic_load(&g_arr[2][tid], RLX, AGT);
#pragma unroll
            for (int off = 32; off; off >>= 1) m = min(m, __shfl_xor(m, off, 64));
            if (lane == 0 && wv < 2) red_bar[wv] = m;
            __syncthreads();
            if (tid == 0) bar_done = (min(red_bar[0], red_bar[1]) >= tp1);
            __syncthreads();
            if (bar_done) break;
            __builtin_amdgcn_s_sleep(1);
        }
    }
}

// ---------------- K4: scores + mean(exp(score)) ----------------
__global__ void k_final(float* __restrict__ out) {
    const int b = threadIdx.x;  // 64 threads
    float e = 0.f;
    if (b < BB) {
        const float sc = g_score[b];
        out[BB * TT + b] = sc;
        e = expf(sc);
    }
#pragma unroll
    for (int off = 32; off; off >>= 1) e += __shfl_xor(e, off, 64);
    if (b == 0) out[BB * TT + BB] = e / (float)BB;
}

extern "C" void kernel_launch(void* const* d_in, const int* in_sizes, int n_in,
                              void* d_out, int out_size, void* d_ws, size_t ws_size,
                              hipStream_t stream) {
    const float* enc  = (const float*)d_in[0];
    const float* emb  = (const float*)d_in[1];
    const float* Wih  = (const float*)d_in[2];
    const float* Whh  = (const float*)d_in[3];
    const float* bl   = (const float*)d_in[4];
    const float* Wenc = (const float*)d_in[5];
    const float* Wdec = (const float*)d_in[6];
    const float* bj   = (const float*)d_in[7];
    const float* Wout = (const float*)d_in[8];
    float* out = (float*)d_out;

    hipLaunchKernelGGL(k_encproj, dim3(TT), dim3(256), 0, stream, enc, Wenc);
    hipLaunchKernelGGL(k_embproj, dim3(128), dim3(256), 0, stream, emb, Wih);
    hipLaunchKernelGGL(k_init, dim3(1), dim3(512), 0, stream, bl);

    void* args[] = { (void*)&Wdec, (void*)&Wout, (void*)&Whh,
                     (void*)&bj, (void*)&bl, (void*)&out };
    hipLaunchCooperativeKernel((const void*)k_loop, dim3(NB), dim3(NT), args, 0, stream);

    hipLaunchKernelGGL(k_final, dim3(1), dim3(64), 0, stream, out);
}

// Round 6
// 26061.246 us; speedup vs baseline: 1.2189x; 1.2189x over previous
//
#include <hip/hip_runtime.h>
#include <math.h>

#define BB 32
#define TT 1000
#define HH 512
#define JJ 512
#define VV 1024
#define G4 2048
#define NB 128
#define NT 1024

#define RLX __ATOMIC_RELAXED
#define AGT __HIP_MEMORY_SCOPE_AGENT

// ---- persistent device-side scratch ----
__device__ __align__(16) float g_encp[(size_t)TT * JJ * BB];  // [t][j][b]
__device__ __align__(16) float g_E[(size_t)VV * G4];          // [v][g]
__device__ __align__(16) float g_h[HH * BB];                  // [k][b] (== out_PN)
__device__ __align__(16) float g_c[BB * HH];                  // [b][k]
__device__ __align__(16) float g_joint[JJ * BB];              // [j][b]
__device__ __align__(16) float g_hW[BB * G4];                 // [b][g]
__device__ float g_pm[BB * NB];                               // [b][blk] partial max
__device__ float g_ps[BB * NB];                               // [b][blk] partial sumexp
__device__ int   g_pa[BB * NB];                               // [b][blk] partial argmax
__device__ float g_score[BB];
// producer tags (monotonic step counters), spread 16B to cut line fan-in
__device__ int g_tagJ[NB * 4];   // joint(t) published
__device__ int g_tagS[NB * 4];   // stats(t) published
__device__ int g_tagH[NB * 4];   // h(t)    published (init 0 == h(0) ready)

// ---------------- K0: enc_proj[t][j][b] ----------------
__global__ __launch_bounds__(256) void k_encproj(const float* __restrict__ enc,
                                                 const float* __restrict__ Wenc) {
    __shared__ __align__(16) float x[BB * 512];
    const int t = blockIdx.x;
    for (int i = threadIdx.x; i < BB * 128; i += 256) {
        const int b = i >> 7, k4 = i & 127;
        *reinterpret_cast<float4*>(x + b * 512 + k4 * 4) =
            *reinterpret_cast<const float4*>(enc + ((size_t)(b * TT + t)) * 512 + k4 * 4);
    }
    __syncthreads();
    const int j = threadIdx.x;
    float acc0[BB], acc1[BB];
#pragma unroll
    for (int b = 0; b < BB; ++b) { acc0[b] = 0.f; acc1[b] = 0.f; }
    for (int k4 = 0; k4 < 128; ++k4) {
        const int k = k4 * 4;
        float w0[4], w1[4];
#pragma unroll
        for (int i = 0; i < 4; ++i) {
            w0[i] = Wenc[(size_t)(k + i) * JJ + j];
            w1[i] = Wenc[(size_t)(k + i) * JJ + j + 256];
        }
#pragma unroll
        for (int b = 0; b < BB; ++b) {
            const float4 xv = *reinterpret_cast<const float4*>(x + b * 512 + k);
            acc0[b] += xv.x * w0[0] + xv.y * w0[1] + xv.z * w0[2] + xv.w * w0[3];
            acc1[b] += xv.x * w1[0] + xv.y * w1[1] + xv.z * w1[2] + xv.w * w1[3];
        }
    }
    float* outt = g_encp + (size_t)t * JJ * BB;
#pragma unroll
    for (int b = 0; b < BB; ++b) {
        outt[j * BB + b]         = acc0[b];
        outt[(j + 256) * BB + b] = acc1[b];
    }
}

// ---------------- K1: E = embed @ W_ih ----------------
__global__ __launch_bounds__(256) void k_embproj(const float* __restrict__ emb,
                                                 const float* __restrict__ Wih) {
    __shared__ __align__(16) float x[BB * 512];
    const int v0 = (blockIdx.x >> 2) * 32;
    const int g0 = (blockIdx.x & 3) * 512;
    for (int i = threadIdx.x; i < BB * 128; i += 256) {
        const int b = i >> 7, k4 = i & 127;
        *reinterpret_cast<float4*>(x + b * 512 + k4 * 4) =
            *reinterpret_cast<const float4*>(emb + (size_t)(v0 + b) * 512 + k4 * 4);
    }
    __syncthreads();
    const int j = g0 + threadIdx.x;
    float acc0[BB], acc1[BB];
#pragma unroll
    for (int b = 0; b < BB; ++b) { acc0[b] = 0.f; acc1[b] = 0.f; }
    for (int k4 = 0; k4 < 128; ++k4) {
        const int k = k4 * 4;
        float w0[4], w1[4];
#pragma unroll
        for (int i = 0; i < 4; ++i) {
            w0[i] = Wih[(size_t)(k + i) * G4 + j];
            w1[i] = Wih[(size_t)(k + i) * G4 + j + 256];
        }
#pragma unroll
        for (int b = 0; b < BB; ++b) {
            const float4 xv = *reinterpret_cast<const float4*>(x + b * 512 + k);
            acc0[b] += xv.x * w0[0] + xv.y * w0[1] + xv.z * w0[2] + xv.w * w0[3];
            acc1[b] += xv.x * w1[0] + xv.y * w1[1] + xv.z * w1[2] + xv.w * w1[3];
        }
    }
#pragma unroll
    for (int b = 0; b < BB; ++b) {
        g_E[(size_t)(v0 + b) * G4 + j]       = acc0[b];
        g_E[(size_t)(v0 + b) * G4 + j + 256] = acc1[b];
    }
}

// ---------------- K2: initial LSTM step + state/tag reset ----------------
__global__ void k_init(const float* __restrict__ bl) {
    const int k = threadIdx.x;  // 512
    const float ig = g_E[k]        + bl[k];
    const float gg = g_E[1024 + k] + bl[1024 + k];
    const float og = g_E[1536 + k] + bl[1536 + k];
    const float si = 1.f / (1.f + expf(-ig));
    const float so = 1.f / (1.f + expf(-og));
    const float c1 = si * tanhf(gg);
    const float h1 = so * tanhf(c1);
    for (int b = 0; b < BB; ++b) {
        g_h[k * BB + b] = h1;
        g_c[b * HH + k] = c1;
    }
    if (k < BB) g_score[k] = 0.f;
    g_tagJ[k] = 0; g_tagS[k] = 0; g_tagH[k] = 0;   // k covers [0,512) = NB*4
}

// 4-col x 32-b tile, K covered by ks-interleaved slices (k = k0 + i*8 + ks).
// w rows padded to `wpad` floats -> conflict-free. Butterfly over ks bits
// leaves the (partial-)K sums in ALL lanes.
template<int KN>
__device__ __forceinline__ void mv4(const float* __restrict__ w_lds, const int wpad,
                                    const int c0, const int k0,
                                    const float* __restrict__ x_lds,
                                    const int ks, const int b4, float acc[4][4]) {
#pragma unroll
    for (int c = 0; c < 4; ++c)
#pragma unroll
        for (int r = 0; r < 4; ++r) acc[c][r] = 0.f;
#pragma unroll 8
    for (int i = 0; i < KN; ++i) {
        const int k = k0 + i * 8 + ks;
        const float4 xv = *reinterpret_cast<const float4*>(x_lds + k * 32 + b4 * 4);
        const float4 wv = *reinterpret_cast<const float4*>(w_lds + k * wpad + c0);
        acc[0][0] += wv.x * xv.x; acc[0][1] += wv.x * xv.y; acc[0][2] += wv.x * xv.z; acc[0][3] += wv.x * xv.w;
        acc[1][0] += wv.y * xv.x; acc[1][1] += wv.y * xv.y; acc[1][2] += wv.y * xv.z; acc[1][3] += wv.y * xv.w;
        acc[2][0] += wv.z * xv.x; acc[2][1] += wv.z * xv.y; acc[2][2] += wv.z * xv.z; acc[2][3] += wv.z * xv.w;
        acc[3][0] += wv.w * xv.x; acc[3][1] += wv.w * xv.y; acc[3][2] += wv.w * xv.z; acc[3][3] += wv.w * xv.w;
    }
#pragma unroll
    for (int off = 8; off <= 32; off <<= 1)
#pragma unroll
        for (int c = 0; c < 4; ++c)
#pragma unroll
            for (int r = 0; r < 4; ++r) acc[c][r] += __shfl_xor(acc[c][r], off, 64);
}

// single-wave tight poll: wave 0 spins until min(tag[0..127]) >= thr.
// No __syncthreads inside the loop; caller syncs after.
__device__ __forceinline__ void tag_poll(const int* tags, int thr, int wv, int lane) {
    if (wv == 0) {
        for (;;) {
            int a = __hip_atomic_load(&tags[lane * 4], RLX, AGT);
            int b = __hip_atomic_load(&tags[(lane + 64) * 4], RLX, AGT);
            int m = min(a, b);
#pragma unroll
            for (int off = 32; off; off >>= 1) m = min(m, __shfl_xor(m, off, 64));
            if (m >= thr) break;
        }
    }
    __syncthreads();
}

// ---------------- K3: persistent scan, producer-tag flow control ----------------
__global__ __launch_bounds__(NT) void k_loop(const float* __restrict__ Wdec,
                                             const float* __restrict__ Wout,
                                             const float* __restrict__ Whh,
                                             const float* __restrict__ bj,
                                             const float* __restrict__ bl,
                                             float* __restrict__ out) {
    __shared__ __align__(16) float x_lds[512 * 32];     // 64 KB: h, then joint
    __shared__ __align__(16) float wab_lds[512 * 20];   // 40 KB: cols 0-15 Whh, 16-19 Wdec
    __shared__ __align__(16) float wout_lds[512 * 12];  // 24 KB: cols 0-7 Wout
    __shared__ float part_lds[560];                     // A: 4x136 quarters; B: 2x160 halves
    __shared__ float logit_lds[8 * 33];
    __shared__ float red_m[2], red_s[2];
    __shared__ int   red_a[2];

    const int blk = blockIdx.x, tid = threadIdx.x;
    const int wv = tid >> 6, lane = tid & 63, ks = lane >> 3, b4 = lane & 7;
    const int row = blk >> 2, qs = blk & 3;   // window-C assignment

    for (int i = tid; i < 512 * 20; i += NT) {
        const int k = i / 20, c = i - k * 20;
        wab_lds[i] = (c < 16) ? Whh[(size_t)k * G4 + blk * 16 + c]
                              : Wdec[(size_t)k * JJ + blk * 4 + (c - 16)];
    }
    for (int i = tid; i < 512 * 12; i += NT) {
        const int k = i / 12, c = i - k * 12;
        wout_lds[i] = (c < 8) ? Wout[(size_t)k * VV + blk * 8 + c] : 0.f;
    }
    float bjr[4];
#pragma unroll
    for (int c = 0; c < 4; ++c) bjr[c] = bj[blk * 4 + c];
    __syncthreads();

    float acc[4][4];
    for (int t = 0; t < TT; ++t) {
        const int tp1 = t + 1;

        // ======== window A: wait h(t); stage h; Whh waves 0-3; Wdec quarters 4-7 -> joint
        float encr[4];
        if (wv == 8 && lane < 32) {   // enc prefetch (cached, independent of tags)
            const float* ep = g_encp + (size_t)t * JJ * BB + (size_t)blk * 4 * BB;
#pragma unroll
            for (int c = 0; c < 4; ++c) encr[c] = ep[c * BB + lane];
        }
        tag_poll(g_tagH, t, wv, lane);          // h(t) ready (init tags 0 == h(0))
        {
            float v[16];
#pragma unroll
            for (int p = 0; p < 16; ++p)
                v[p] = __hip_atomic_load(&g_h[tid + p * 1024], RLX, AGT);
#pragma unroll
            for (int p = 0; p < 16; ++p) x_lds[tid + p * 1024] = v[p];
        }
        __syncthreads();
        if (wv < 4) {                 // hW slice: 4 cols each, full K
            mv4<64>(wab_lds, 20, wv * 4, 0, x_lds, ks, b4, acc);
            if (ks == 0) {
#pragma unroll
                for (int c = 0; c < 4; ++c)
#pragma unroll
                    for (int j = 0; j < 4; ++j)
                        __hip_atomic_store(&g_hW[(size_t)(b4 * 4 + j) * G4 + blk * 16 + wv * 4 + c],
                                           acc[c][j], RLX, AGT);
            }
        } else if (wv < 8) {          // Wdec quarter-K partials
            mv4<16>(wab_lds, 20, 16, (wv - 4) * 128, x_lds, ks, b4, acc);
            if (ks == 0) {
#pragma unroll
                for (int c = 0; c < 4; ++c)
#pragma unroll
                    for (int j = 0; j < 4; ++j)
                        part_lds[(wv - 4) * 136 + c * 33 + b4 * 4 + j] = acc[c][j];
            }
        }
        __syncthreads();
        if (wv == 8 && lane < 32) {   // combine quarters + enc + bias -> joint
            const int b = lane;
#pragma unroll
            for (int c = 0; c < 4; ++c) {
                const float u = part_lds[c * 33 + b] + part_lds[136 + c * 33 + b]
                              + part_lds[272 + c * 33 + b] + part_lds[408 + c * 33 + b]
                              + encr[c] + bjr[c];
                __hip_atomic_store(&g_joint[(blk * 4 + c) * BB + b], tanhf(u), RLX, AGT);
            }
        }
        __syncthreads();              // all joint/hW stores drained (vmcnt 0 per wave)
        if (tid == 0) __hip_atomic_store(&g_tagJ[blk * 4], tp1, RLX, AGT);

        // ======== window B: wait joint(t); stage; Wout tiles -> logits -> stats
        tag_poll(g_tagJ, tp1, wv, lane);
        {
            float v[16];
#pragma unroll
            for (int p = 0; p < 16; ++p)
                v[p] = __hip_atomic_load(&g_joint[tid + p * 1024], RLX, AGT);
#pragma unroll
            for (int p = 0; p < 16; ++p) x_lds[tid + p * 1024] = v[p];
        }
        __syncthreads();
        if (wv < 4) {
            const int tile = wv & 1, kh = wv >> 1;
            mv4<32>(wout_lds, 12, tile * 4, kh * 256, x_lds, ks, b4, acc);
            if (kh == 1 && ks == 0) {
#pragma unroll
                for (int c = 0; c < 4; ++c)
#pragma unroll
                    for (int j = 0; j < 4; ++j)
                        part_lds[tile * 160 + c * 33 + b4 * 4 + j] = acc[c][j];
            }
        }
        __syncthreads();
        if (wv < 2 && ks == 0) {      // combine K-halves, stash logits
#pragma unroll
            for (int c = 0; c < 4; ++c)
#pragma unroll
                for (int j = 0; j < 4; ++j)
                    logit_lds[(wv * 4 + c) * 33 + b4 * 4 + j] =
                        acc[c][j] + part_lds[wv * 160 + c * 33 + b4 * 4 + j];
        }
        __syncthreads();
        if (wv == 0 && lane < BB) {   // per-b stats over this block's 8 cols
            const int b = lane;
            float m = -1e30f; int a = 0;
#pragma unroll
            for (int c = 0; c < 8; ++c) {
                const float l = logit_lds[c * 33 + b];
                if (l > m) { m = l; a = blk * 8 + c; }
            }
            float s = 0.f;
#pragma unroll
            for (int c = 0; c < 8; ++c) s += expf(logit_lds[c * 33 + b] - m);
            __hip_atomic_store(&g_pm[b * NB + blk], m, RLX, AGT);
            __hip_atomic_store(&g_pa[b * NB + blk], a, RLX, AGT);
            __hip_atomic_store(&g_ps[b * NB + blk], s, RLX, AGT);
        }
        __syncthreads();              // stats stores drained
        if (tid == 0) __hip_atomic_store(&g_tagS[blk * 4], tp1, RLX, AGT);

        // ======== window C: wait stats(t); block 4r+q: reduce row r, LSTM k-slice q
        tag_poll(g_tagS, tp1, wv, lane);
        {
            float m0 = -1e30f, s0 = 0.f; int a0 = 1 << 30;
            if (tid < NB) {
                m0 = __hip_atomic_load(&g_pm[row * NB + tid], RLX, AGT);
                a0 = __hip_atomic_load(&g_pa[row * NB + tid], RLX, AGT);
                s0 = __hip_atomic_load(&g_ps[row * NB + tid], RLX, AGT);
            }
            float m = m0; int a = a0;
#pragma unroll
            for (int off = 32; off; off >>= 1) {
                const float om = __shfl_xor(m, off, 64);
                const int   oa = __shfl_xor(a, off, 64);
                if (om > m || (om == m && oa < a)) { m = om; a = oa; }
            }
            if (lane == 0 && wv < 2) { red_m[wv] = m; red_a[wv] = a; }
            __syncthreads();
            float M; int P;
            {
                const float ma = red_m[0], mb = red_m[1];
                const int aa = red_a[0], ab = red_a[1];
                if (mb > ma || (mb == ma && ab < aa)) { M = mb; P = ab; }
                else { M = ma; P = aa; }
            }
            float e = (tid < NB) ? s0 * expf(m0 - M) : 0.f;
#pragma unroll
            for (int off = 32; off; off >>= 1) e += __shfl_xor(e, off, 64);
            if (lane == 0 && wv < 2) red_s[wv] = e;
            __syncthreads();
            if (qs == 0 && tid == 0) {
                out[row * TT + t] = (float)P;
                if (P != 0) g_score[row] += -logf(red_s[0] + red_s[1]);
            }
            if (P != 0 && tid < 128) {   // LSTM k-slice: k in [qs*128, qs*128+128)
                const int k = qs * 128 + tid;
                const float* Ep = g_E + (size_t)P * G4;
                const float hw0 = __hip_atomic_load(&g_hW[(size_t)row * G4 + k],        RLX, AGT);
                const float hw1 = __hip_atomic_load(&g_hW[(size_t)row * G4 + 512 + k],  RLX, AGT);
                const float hw2 = __hip_atomic_load(&g_hW[(size_t)row * G4 + 1024 + k], RLX, AGT);
                const float hw3 = __hip_atomic_load(&g_hW[(size_t)row * G4 + 1536 + k], RLX, AGT);
                const float i_g = Ep[k]        + hw0 + bl[k];
                const float f_g = Ep[512 + k]  + hw1 + bl[512 + k];
                const float g_g = Ep[1024 + k] + hw2 + bl[1024 + k];
                const float o_g = Ep[1536 + k] + hw3 + bl[1536 + k];
                const float si = 1.f / (1.f + expf(-i_g));
                const float sf = 1.f / (1.f + expf(-f_g));
                const float so = 1.f / (1.f + expf(-o_g));
                const float cn = sf * g_c[row * HH + k] + si * tanhf(g_g);
                const float hn = so * tanhf(cn);
                g_c[row * HH + k] = cn;                          // block-private
                __hip_atomic_store(&g_h[k * BB + row], hn, RLX, AGT);
            }
        }
        __syncthreads();              // h stores drained
        if (tid == 0) __hip_atomic_store(&g_tagH[blk * 4], tp1, RLX, AGT);
        // next iteration's head polls g_tagH >= t+1
    }
}

// ---------------- K4: scores + mean(exp(score)) ----------------
__global__ void k_final(float* __restrict__ out) {
    const int b = threadIdx.x;  // 64 threads
    float e = 0.f;
    if (b < BB) {
        const float sc = g_score[b];
        out[BB * TT + b] = sc;
        e = expf(sc);
    }
#pragma unroll
    for (int off = 32; off; off >>= 1) e += __shfl_xor(e, off, 64);
    if (b == 0) out[BB * TT + BB] = e / (float)BB;
}

extern "C" void kernel_launch(void* const* d_in, const int* in_sizes, int n_in,
                              void* d_out, int out_size, void* d_ws, size_t ws_size,
                              hipStream_t stream) {
    const float* enc  = (const float*)d_in[0];
    const float* emb  = (const float*)d_in[1];
    const float* Wih  = (const float*)d_in[2];
    const float* Whh  = (const float*)d_in[3];
    const float* bl   = (const float*)d_in[4];
    const float* Wenc = (const float*)d_in[5];
    const float* Wdec = (const float*)d_in[6];
    const float* bj   = (const float*)d_in[7];
    const float* Wout = (const float*)d_in[8];
    float* out = (float*)d_out;

    hipLaunchKernelGGL(k_encproj, dim3(TT), dim3(256), 0, stream, enc, Wenc);
    hipLaunchKernelGGL(k_embproj, dim3(128), dim3(256), 0, stream, emb, Wih);
    hipLaunchKernelGGL(k_init, dim3(1), dim3(512), 0, stream, bl);

    void* args[] = { (void*)&Wdec, (void*)&Wout, (void*)&Whh,
                     (void*)&bj, (void*)&bl, (void*)&out };
    hipLaunchCooperativeKernel((const void*)k_loop, dim3(NB), dim3(NT), args, 0, stream);

    hipLaunchKernelGGL(k_final, dim3(1), dim3(64), 0, stream, out);
}